// Round 11
// baseline (209.402 us; speedup 1.0000x reference)
//
#include <hip/hip_runtime.h>

// PointNet fused kernel for MI355X (gfx950) — round 11.
//
// Algebra: segment-MLP + cb are per-row constants -> cancel in the per-row
// min/max rescale. Only s1[m,n] = feat·cW[0:6] + relu(MLP3(feat))·cW[6:262]
// matters, then per-row rescale to [-1,1].
//
// Round-11: counted-vmcnt weight pipeline (fixing R9's vmcnt(0) drain).
// Per ks-step: compute {4 A ds_read + 4 B ds_read + 16 MFMA} from LDS,
// raw s_barrier, issue DMA for tile t+2 into the buffer just freed,
// s_waitcnt vmcnt(2) (tile t+1 ready, t+2 in flight), raw s_barrier.
// Weight L2 latency hides under compute; __syncthreads (which drains
// vmcnt to 0) only at prologue/epilogue. A-reads are lane-linear
// ds_read_b128 with immediate offsets -> ~zero VALU in the hot loop,
// conflict-free. h layout = R10's packed fragments (no XOR swizzle --
// bank-walk shows it was a no-op: reads are full-KB linear either way).
// 128-pt blocks, 8 waves (4 cgrp x 2 pgrp), 102 KB LDS, 1 block/CU.

typedef __attribute__((ext_vector_type(8))) short short8;   // 8 bf16
typedef __attribute__((ext_vector_type(4))) float f32x4;    // MFMA accum
typedef __attribute__((ext_vector_type(4))) unsigned int u32x4;

#define THREADS 512

#define LDS_AS(p) ((__attribute__((address_space(3))) unsigned int*)(p))
#define GLB_AS(p) ((const __attribute__((address_space(1))) unsigned int*)(p))

__device__ __forceinline__ unsigned short f2bf(float f) {
  union { float f; unsigned int u; } x; x.f = f;
  unsigned int r = x.u + 0x7fffu + ((x.u >> 16) & 1u);   // RNE
  return (unsigned short)(r >> 16);
}

__device__ __forceinline__ unsigned int cvt_pk_bf16(float lo, float hi) {
  unsigned int r;
  asm("v_cvt_pk_bf16_f32 %0, %1, %2" : "=v"(r) : "v"(lo), "v"(hi));
  return r;
}

// ---------------------------------------------------------------------------
// k0: pack weights into MFMA A-fragment order (unchanged):
//   idx(s,ct,hi,col,j) = (((s*16+ct)*4+hi)*16+col)*8 + j
//   k = s*32 + hi*8 + j (zero past Kreal), c = ct*16 + col
// Regions (ushort): W1 @0 (8192), W2 @8192 (65536), W3 @73728 (65536)
// ---------------------------------------------------------------------------
__global__ void pn_pack(const float* __restrict__ W1,
                        const float* __restrict__ W2,
                        const float* __restrict__ W3,
                        unsigned short* __restrict__ wp) {
  int e = blockIdx.x * 256 + threadIdx.x;           // 0 .. 139263
  const float* src; int Kreal, base, r;
  if (e < 8192)       { src = W1; Kreal = 6;   base = 0;     r = e; }
  else if (e < 73728) { src = W2; Kreal = 256; base = 8192;  r = e - 8192; }
  else                { src = W3; Kreal = 256; base = 73728; r = e - 73728; }
  int j   = r & 7;
  int col = (r >> 3) & 15;
  int hi  = (r >> 7) & 3;
  int ct  = (r >> 9) & 15;
  int s   = r >> 13;
  int k = s * 32 + hi * 8 + j;
  int c = ct * 16 + col;
  float v = (k < Kreal) ? src[k * 256 + c] : 0.0f;
  wp[base + r] = f2bf(v);
}

// ---------------------------------------------------------------------------
// k1 helpers. 8 waves: cgrp = wave&3 (64 of 256 ch), pgrp = wave>>2 (64 of
// 128 pts). hP packed: frag (ks,pfg) = 512 ushorts at (ks*8+pfg)*512, lane l
// holds h[pt = pfg*16 + (l&15)][ch = ks*32 + (l>>4)*8 + 0..7].
// wst tile: 16 rows (ct) x 512 ushorts, lane-linear per (ct): matches the
// packed-global A-fragment order, so A-read = base + ct*1024B + lane*16B.
// ---------------------------------------------------------------------------

// async-stage one 16 KB ks-tile into LDS; wave w stages rows {w, 8+w}.
__device__ __forceinline__ void stage16k(const unsigned short* __restrict__ gsrc,
                                         unsigned short* lbase,
                                         int wave, int lane) {
#pragma unroll
  for (int r = 0; r < 2; ++r) {
    int row = r * 8 + wave;
    const unsigned short* g = gsrc + row * 512 + lane * 8;   // per-lane src
    unsigned short* l = lbase + row * 512;                   // wave-uniform dst
    __builtin_amdgcn_global_load_lds(GLB_AS(g), LDS_AS(l), 16, 0, 0);
  }
}

// init acc with per-channel bias (broadcast over points)
__device__ __forceinline__ void acc_init(f32x4 (&acc)[4][4], const float* bv,
                                         int cgrp, int hi) {
#pragma unroll
  for (int cf = 0; cf < 4; ++cf) {
    f32x4 bi = *(const f32x4*)(bv + cgrp * 64 + cf * 16 + hi * 4);
#pragma unroll
    for (int pf = 0; pf < 4; ++pf) acc[cf][pf] = bi;
  }
}

// relu -> bf16 -> packed hP fragments (one b64 store per tile)
__device__ __forceinline__ void epi_hp(f32x4 (&acc)[4][4], unsigned short* hP,
                                       int cgrp, int pgrp, int l15, int hi) {
#pragma unroll
  for (int cf = 0; cf < 4; ++cf) {
    int ks2 = cgrp * 2 + (cf >> 1);
    int chi = (cf & 1) * 2 + (hi >> 1);
    int j0  = (hi & 1) * 4;
#pragma unroll
    for (int pf = 0; pf < 4; ++pf) {
      f32x4 a = acc[cf][pf];
      unsigned int lo  = cvt_pk_bf16(fmaxf(a[0], 0.0f), fmaxf(a[1], 0.0f));
      unsigned int hi2 = cvt_pk_bf16(fmaxf(a[2], 0.0f), fmaxf(a[3], 0.0f));
      unsigned long long w = (unsigned long long)lo | ((unsigned long long)hi2 << 32);
      int us = ((ks2 * 8 + pgrp * 4 + pf) * 64 + chi * 16 + l15) * 8 + j0;
      *(unsigned long long*)(hP + us) = w;
    }
  }
}

// ---------------------------------------------------------------------------
// k1: one block = 128 points of one bbox row; 8 waves; ~102 KB LDS, 1 blk/CU.
// 16-step K-stream (t<8: W2, t>=8: W3) with 2-deep DMA prefetch.
// ---------------------------------------------------------------------------
__global__ __launch_bounds__(THREADS, 1) void pn_main(
    const float* __restrict__ feat,
    const unsigned short* __restrict__ wp,
    const float* __restrict__ b1,
    const float* __restrict__ b2,
    const float* __restrict__ b3,
    const float* __restrict__ cW,
    float* __restrict__ out) {
  __shared__ unsigned short hP[8 * 8 * 512];     // 64 KB packed h (in-place)
  __shared__ unsigned short wst[2][16 * 512];    // 32 KB weight tile ping-pong
  __shared__ unsigned short hF[128 * 8];         // 2 KB layer-1 B slice
  __shared__ float biasL[3 * 256];               // 3 KB
  __shared__ float whL[256];                     // 1 KB (cW[6..261])
  float* sPart = (float*)hF;                     // overlay: hF dead after L1

  const int tid  = threadIdx.x;
  const int lane = tid & 63;
  const int wave = tid >> 6;
  const int l15  = lane & 15;
  const int hi   = lane >> 4;
  const int cgrp = wave & 3;     // channel group (64 of 256)
  const int pgrp = wave >> 2;    // point group (64 of 128)

  const int blk = blockIdx.x;
  const int m   = blk >> 6;                  // 64 blocks per bbox row
  const int n0  = (blk & 63) << 7;
  const int g0  = m * 8192 + n0;

  // ---- kick off DMA for K-stream tiles 0 and 1 first (oldest vmem ops)
  stage16k(wp + 8192, wst[0], wave, lane);             // W2 ks0
  stage16k(wp + 8192 + 8192, wst[1], wave, lane);      // W2 ks1

  // ---- stage biases + classifier hidden weights
  if (tid < 256) {
    biasL[tid]       = b1[tid];
    biasL[256 + tid] = b2[tid];
    biasL[512 + tid] = b3[tid];
    whL[tid]         = cW[6 + tid];
  }

  // ---- build hF (k0..7 slice, 2 zeros) + fdot in register
  float fdot = 0.0f;
  if (tid < 128) {
    const float* fp = feat + (size_t)(g0 + tid) * 6;
    float f0 = fp[0], f1 = fp[1], f2 = fp[2], f3 = fp[3], f4 = fp[4], f5 = fp[5];
    fdot = f0 * cW[0] + f1 * cW[1] + f2 * cW[2] + f3 * cW[3] + f4 * cW[4] + f5 * cW[5];
    u32x4 v;
    v[0] = cvt_pk_bf16(f0, f1);
    v[1] = cvt_pk_bf16(f2, f3);
    v[2] = cvt_pk_bf16(f4, f5);
    v[3] = 0;
    *(u32x4*)(hF + tid * 8) = v;
  }

  // ---- W1 fragments straight from L2 (tiny, once)
  short8 w1r[4];
#pragma unroll
  for (int cf = 0; cf < 4; ++cf)
    w1r[cf] = *(const short8*)(wp + ((((cgrp * 4 + cf) * 4 + hi) * 16 + l15) << 3));

  __syncthreads();   // hF/bias visible; drains vmcnt -> tiles 0,1 staged too

  f32x4 acc[4][4];
  const short8 zero8 = {0, 0, 0, 0, 0, 0, 0, 0};

  // ---- layer 1 (K padded to 32; only hi==0 k-slots nonzero)
  acc_init(acc, biasL + 0, cgrp, hi);
#pragma unroll
  for (int pf = 0; pf < 4; ++pf) {
    int p = pgrp * 64 + pf * 16 + l15;
    short8 b = (hi == 0) ? *(const short8*)(hF + p * 8) : zero8;
#pragma unroll
    for (int cf = 0; cf < 4; ++cf)
      acc[cf][pf] = __builtin_amdgcn_mfma_f32_16x16x32_bf16(
          w1r[cf], b, acc[cf][pf], 0, 0, 0);
  }
  epi_hp(acc, hP, cgrp, pgrp, l15, hi);      // h1 -> hP
  acc_init(acc, biasL + 256, cgrp, hi);      // pre-init for layer 2
  __syncthreads();                           // h1 visible

  // ---- 16-step K-stream: t<8 -> W2 (reads h1), t>=8 -> W3 (reads h2)
#pragma unroll 1
  for (int t = 0; t < 16; ++t) {
    const unsigned short* wt = wst[t & 1];
    int ksl = t & 7;
    short8 afr[4], bfr[4];
#pragma unroll
    for (int cf = 0; cf < 4; ++cf)           // A: lane-linear 1 KB, imm offset
      afr[cf] = *(const short8*)(wt + (((cgrp * 4 + cf) * 64 + lane) << 3));
#pragma unroll
    for (int pf = 0; pf < 4; ++pf)           // B: lane-linear 1 KB, imm offset
      bfr[pf] = *(const short8*)(hP + (((ksl * 8 + pgrp * 4 + pf) * 64 + lane) << 3));
#pragma unroll
    for (int cf = 0; cf < 4; ++cf)
#pragma unroll
      for (int pf = 0; pf < 4; ++pf)
        acc[cf][pf] = __builtin_amdgcn_mfma_f32_16x16x32_bf16(
            afr[cf], bfr[pf], acc[cf][pf], 0, 0, 0);

    if (t == 7) {
      // layer boundary: h1 reads done after barrier; write h2; W3 ks0 was
      // staged at t=6, W3 ks1 issued here -> counted wait keeps it in flight.
      __builtin_amdgcn_sched_barrier(0);
      __builtin_amdgcn_s_barrier();                       // h1 + wst[1] reads done
      __builtin_amdgcn_sched_barrier(0);
      stage16k(wp + 73728 + 8192, wst[1], wave, lane);    // stage tile 9 (W3 ks1)
      epi_hp(acc, hP, cgrp, pgrp, l15, hi);               // h2 -> hP
      acc_init(acc, biasL + 512, cgrp, hi);               // init for layer 3
      asm volatile("s_waitcnt vmcnt(2) lgkmcnt(0)" ::: "memory");
      __builtin_amdgcn_sched_barrier(0);
      __builtin_amdgcn_s_barrier();                       // h2 + tile 8 ready
    } else {
      __builtin_amdgcn_sched_barrier(0);
      __builtin_amdgcn_s_barrier();                       // buffer reads done
      __builtin_amdgcn_sched_barrier(0);
      if (t + 2 < 16) {
        int s = t + 2;
        const unsigned short* src = (s < 8) ? (wp + 8192 + s * 8192)
                                            : (wp + 73728 + (s - 8) * 8192);
        stage16k(src, wst[t & 1], wave, lane);            // overwrite freed buf
        asm volatile("s_waitcnt vmcnt(2)" ::: "memory");  // tile t+1 ready
      } else {
        asm volatile("s_waitcnt vmcnt(0)" ::: "memory");  // drain tail
      }
      __builtin_amdgcn_sched_barrier(0);
      __builtin_amdgcn_s_barrier();                       // next tile visible
    }
  }

  // ---- classifier dot + per-point reduce (acc holds layer-3 result)
  float part[4] = {0.f, 0.f, 0.f, 0.f};
#pragma unroll
  for (int cf = 0; cf < 4; ++cf) {
    int c0 = cgrp * 64 + cf * 16 + hi * 4;
#pragma unroll
    for (int r = 0; r < 4; ++r) {
      float wv = whL[c0 + r];
#pragma unroll
      for (int pf = 0; pf < 4; ++pf)
        part[pf] += fmaxf(acc[cf][pf][r], 0.0f) * wv;
    }
  }
#pragma unroll
  for (int off = 16; off < 64; off <<= 1)
#pragma unroll
    for (int pf = 0; pf < 4; ++pf)
      part[pf] += __shfl_xor(part[pf], off);
  if (hi == 0) {
#pragma unroll
    for (int pf = 0; pf < 4; ++pf)
      sPart[cgrp * 128 + pgrp * 64 + pf * 16 + l15] = part[pf];
  }
  __syncthreads();

  if (tid < 128) {
    float s = sPart[tid] + sPart[128 + tid] + sPart[256 + tid] + sPart[384 + tid]
            + fdot;
    out[g0 + tid] = s;   // raw s1; rescaled by pn_finalize
  }
}

// ---------------------------------------------------------------------------
// k2: per-bbox min/max rescale to [-1,1], in place.
// ---------------------------------------------------------------------------
__global__ void pn_finalize(float* __restrict__ out) {
  __shared__ float smn[4], smx[4];
  int mrow = blockIdx.x;
  float* row = out + mrow * 8192;
  float v[32];
  float mn = 1e30f, mx = -1e30f;
#pragma unroll
  for (int i = 0; i < 32; ++i) {
    v[i] = row[threadIdx.x + i * 256];
    mn = fminf(mn, v[i]);
    mx = fmaxf(mx, v[i]);
  }
#pragma unroll
  for (int off = 1; off < 64; off <<= 1) {
    mn = fminf(mn, __shfl_xor(mn, off));
    mx = fmaxf(mx, __shfl_xor(mx, off));
  }
  int w = threadIdx.x >> 6;
  if ((threadIdx.x & 63) == 0) { smn[w] = mn; smx[w] = mx; }
  __syncthreads();
  mn = fminf(fminf(smn[0], smn[1]), fminf(smn[2], smn[3]));
  mx = fmaxf(fmaxf(smx[0], smx[1]), fmaxf(smx[2], smx[3]));
  float sc = 2.0f / (mx - mn);
#pragma unroll
  for (int i = 0; i < 32; ++i)
    row[threadIdx.x + i * 256] = (v[i] - mn) * sc - 1.0f;
}

// ---------------------------------------------------------------------------
extern "C" void kernel_launch(void* const* d_in, const int* in_sizes, int n_in,
                              void* d_out, int out_size, void* d_ws, size_t ws_size,
                              hipStream_t stream) {
  const float* feat = (const float*)d_in[0];
  const float* eW1  = (const float*)d_in[1];
  const float* eb1  = (const float*)d_in[2];
  const float* eW2  = (const float*)d_in[3];
  const float* eb2  = (const float*)d_in[4];
  const float* eW3  = (const float*)d_in[5];
  const float* eb3  = (const float*)d_in[6];
  // sW*/sb* (7..12) and cb (14) cancel in the per-row rescale -- unused.
  const float* cW   = (const float*)d_in[13];
  float* out = (float*)d_out;
  unsigned short* wpack = (unsigned short*)d_ws;   // 278,528 B of ws

  pn_pack<<<544, 256, 0, stream>>>(eW1, eW2, eW3, wpack);
  pn_main<<<4096, THREADS, 0, stream>>>(feat, wpack, eb1, eb2, eb3, cW, out);
  pn_finalize<<<64, 256, 0, stream>>>(out);
}